// Round 11
// baseline (179.576 us; speedup 1.0000x reference)
//
#include <hip/hip_runtime.h>

// CGLayer: MAX_L=2, B=2, N=256, TAU=16 — 2-kernel pipeline.
// Identity: sum_j of edge-level CG(rep, sph) commutes with the j-sum because rep is
// broadcast along j => per-node work after S[bi][m2] = sum_j s[bi][j][m2].
// k_prep: vmp + S + wnl transpose (+ zero finish counter).
// k_main: CG products + mixing; LAST BLOCK (threadfence + atomic counter, the
// round-5-validated cross-XCD pattern) reduces partials and normalizes in place.

#define TAU 16

// ws layout (floats)
#define CNT_OFF  0        // 1 int finish counter (zeroed by k_prep)
#define PART_OFF 768      // 3*512 per-block partial sums [l][bi]
#define VMP_OFF  4096     // 512*144
#define S_OFF    77824    // 512*16 (9 used)
#define WT_OFF   86016    // 15*4096 transposed wnl tiles [tile][tc][cd]

// ---------------- compile-time CG table ----------------
constexpr double cfact(int n){ double r=1.0; for(int i=2;i<=n;i++) r*=i; return r; }
constexpr double csqrt(double x){
  if (x<=0.0) return 0.0;
  double g = x<1.0 ? 1.0 : x;
  for (int i=0;i<80;i++) g = 0.5*(g + x/g);
  return g;
}
constexpr double cg_c(int j1,int j2,int j3,int m1,int m2,int m3){
  if (m1+m2 != m3) return 0.0;
  double pre = csqrt((2.0*j3+1.0)*cfact(j3+j1-j2)*cfact(j3-j1+j2)*cfact(j1+j2-j3)/cfact(j1+j2+j3+1));
  pre *= csqrt(cfact(j3+m3)*cfact(j3-m3)*cfact(j1-m1)*cfact(j1+m1)*cfact(j2-m2)*cfact(j2+m2));
  int kmin = 0;
  if (j2-j3-m1 > kmin) kmin = j2-j3-m1;
  if (j1-j3+m2 > kmin) kmin = j1-j3+m2;
  int kmax = j1+j2-j3;
  if (j1-m1 < kmax) kmax = j1-m1;
  if (j2+m2 < kmax) kmax = j2+m2;
  double s = 0.0;
  for (int k=kmin;k<=kmax;k++){
    double d = cfact(k)*cfact(j1+j2-j3-k)*cfact(j1-m1-k)*cfact(j2+m2-k)*cfact(j3-j2+m1+k)*cfact(j3-j1-m2+k);
    s += (k & 1) ? (-1.0/d) : (1.0/d);
  }
  return pre*s;
}
struct CGTab { float v[615]; };
constexpr CGTab gen_cg(){
  CGTab t{};
  const int TRI[15][3] = {
    {0,0,0},{0,1,1},{0,2,2},{1,0,1},{1,1,0},{1,1,1},{1,1,2},{1,2,1},{1,2,2},
    {2,0,2},{2,1,1},{2,1,2},{2,2,0},{2,2,1},{2,2,2}};
  int off = 0;
  for (int tr=0;tr<15;tr++){
    const int l1=TRI[tr][0], l2=TRI[tr][1], l=TRI[tr][2];
    for (int i1=0;i1<2*l1+1;i1++)
      for (int i2=0;i2<2*l2+1;i2++)
        for (int ik=0;ik<2*l+1;ik++)
          t.v[off++] = (float)cg_c(l1,l2,l,i1-l1,i2-l2,ik-l);
  }
  return t;
}
constexpr CGTab CG = gen_cg();

constexpr int OFF3[27] = {
  0,-1,-1,  -1,1,-1,   -1,-1,10,
  -1,35,-1, 44,53,80,  -1,125,170,
  -1,-1,245,-1,270,315,390,415,490};
constexpr int PAIRS[3][6][2] = {
  {{0,0},{1,1},{2,2},{0,0},{0,0},{0,0}},
  {{0,1},{1,0},{1,1},{1,2},{2,1},{2,2}},
  {{0,2},{1,1},{1,2},{2,0},{2,1},{2,2}}};
constexpr int VOFF[3]   = {0,16,64};
constexpr int SOFF[3]   = {0,1,4};
constexpr int OUT_OFF[3]= {0,8192,32768};
constexpr int NPAIR[3]  = {3,6,6};
constexpr int FOFF[9]   = {0,16,32,48,64,80,96,112,128};
constexpr int WROFF[3]  = {0,768,2304};
constexpr int WTL[3]    = {0,12288,36864};
constexpr int ROWB[3]   = {0,3,21};

__device__ constexpr int RIDX(int l, int mi){ return l==0 ? 0 : (l==1 ? 1+mi : 4+mi); }

// ---------------- K1: vmp + S + wnl transpose + zero counter ----------------
__global__ __launch_bounds__(512)
void k_prep(const float* __restrict__ v0, const float* __restrict__ v1, const float* __restrict__ v2,
            const float* __restrict__ s0, const float* __restrict__ s1, const float* __restrict__ s2,
            const float* __restrict__ wnl0, const float* __restrict__ wnl1, const float* __restrict__ wnl2,
            const int* __restrict__ conn, float* __restrict__ ws)
{
  __shared__ float sh_conn[256];
  __shared__ float sh_v[2][144];
  const int t  = threadIdx.x;
  const int bi = blockIdx.x;
  const int b  = bi >> 8;

  if (t < 256) sh_conn[t] = (float)conn[((size_t)bi<<8) + t];
  __syncthreads();

  if (t < 288) {
    // vmp half h: sum over j in [h*128, h*128+128)
    const int h = (t >= 144) ? 1 : 0;
    const int tt = t - h*144;
    int l, m, c;
    if (tt < 16)      { l=0; m=0;          c=tt;    }
    else if (tt < 64) { l=1; m=(tt-16)>>4; c=tt&15; }
    else              { l=2; m=(tt-64)>>4; c=tt&15; }
    const float* vl = (l==0) ? v0 : (l==1) ? v1 : v2;
    const int dm = 2*l+1;
    const int stride = dm*TAU;
    const float* base = vl + (((size_t)b*256 + h*128)*dm + m)*TAU + c;
    const float* cr = &sh_conn[h*128];
    float a[8];
    #pragma unroll
    for (int q=0;q<8;q++) a[q]=0.f;
    for (int j=0;j<128;j+=8){
      #pragma unroll
      for (int q=0;q<8;q++) a[q] += cr[j+q]*base[(j+q)*stride];
    }
    sh_v[h][tt] = ((a[0]+a[1])+(a[2]+a[3])) + ((a[4]+a[5])+(a[6]+a[7]));
  } else if (t >= 320 && t < 384) {
    // S[bi][9] = sum_j s_l[bi][j][m] — one wave, shfl reduce
    const int lane = t - 320;
    const float* p0 = s0 + (size_t)bi*256;
    const float* p1 = s1 + (size_t)bi*768;
    const float* p2 = s2 + (size_t)bi*1280;
    float a[9];
    #pragma unroll
    for (int m=0;m<9;m++) a[m]=0.f;
    #pragma unroll
    for (int q=0;q<4;q++){
      const int j = lane + q*64;
      a[0] += p0[j];
      a[1] += p1[3*j+0]; a[2] += p1[3*j+1]; a[3] += p1[3*j+2];
      #pragma unroll
      for (int k=0;k<5;k++) a[4+k] += p2[5*j+k];
    }
    #pragma unroll
    for (int m=0;m<9;m++){
      #pragma unroll
      for (int off=32; off; off>>=1) a[m] += __shfl_xor(a[m], off);
    }
    if (lane == 0) {
      #pragma unroll
      for (int m=0;m<9;m++) ws[S_OFF + (size_t)bi*16 + m] = a[m];
    }
  } else if (t >= 448 && bi < 15) {
    // transpose wnl tile bi: wT[tc][cd] = w[cd][tc]
    const int tile = bi;
    const float* src = (tile<3) ? (wnl0 + (size_t)tile*4096)
                     : (tile<9) ? (wnl1 + (size_t)(tile-3)*4096)
                                : (wnl2 + (size_t)(tile-9)*4096);
    float* dst = ws + WT_OFF + (size_t)tile*4096;
    const int q = t - 448;
    #pragma unroll
    for (int r=0;r<4;r++){
      const int cd = q + r*64;
      const float4 r0 = *(const float4*)(src + cd*16);
      const float4 r1 = *(const float4*)(src + cd*16 + 4);
      const float4 r2 = *(const float4*)(src + cd*16 + 8);
      const float4 r3 = *(const float4*)(src + cd*16 + 12);
      dst[ 0*256+cd]=r0.x; dst[ 1*256+cd]=r0.y; dst[ 2*256+cd]=r0.z; dst[ 3*256+cd]=r0.w;
      dst[ 4*256+cd]=r1.x; dst[ 5*256+cd]=r1.y; dst[ 6*256+cd]=r1.z; dst[ 7*256+cd]=r1.w;
      dst[ 8*256+cd]=r2.x; dst[ 9*256+cd]=r2.y; dst[10*256+cd]=r2.z; dst[11*256+cd]=r2.w;
      dst[12*256+cd]=r3.x; dst[13*256+cd]=r3.y; dst[14*256+cd]=r3.z; dst[15*256+cd]=r3.w;
    }
  } else if (t == 400 && bi == 0) {
    // zero the finish counter (device-scope; visible to k_main after kernel end)
    __hip_atomic_store((int*)(ws + CNT_OFF), 0, __ATOMIC_RELAXED, __HIP_MEMORY_SCOPE_AGENT);
  }
  __syncthreads();
  if (t < 144) ws[VMP_OFF + (size_t)bi*144 + t] = sh_v[0][t] + sh_v[1][t];
}

// ---------------- K2 helpers ----------------
template<int L, int P>
__device__ __forceinline__ void build_p(float* __restrict__ dst,
                                        const float (&v_c)[9], const float (&v_d)[9], int tt){
  constexpr int l1 = PAIRS[L][P][0], l2 = PAIRS[L][P][1];
  constexpr int d2 = 2*l2+1, dkk = 2*L+1;
  constexpr int coff = OFF3[l1*9+l2*3+L];
  constexpr int row0 = ROWB[L] + P*dkk;
  #pragma unroll
  for (int kk=0; kk<dkk; kk++){
    const int m = kk - L;
    float a = 0.f;
    #pragma unroll
    for (int m1=-l1; m1<=l1; m1++){
      const int m2 = m - m1;
      if (m2 >= -l2 && m2 <= l2){
        const float C = CG.v[coff + ((m1+l1)*d2 + (m2+l2))*dkk + kk];
        a += C * v_c[RIDX(l1,m1+l1)] * v_d[RIDX(l2,m2+l2)];
      }
    }
    dst[(row0 + kk)*256 + tt] = a;
  }
}

template<int L>
__device__ __forceinline__ void mixl(const float* __restrict__ wt, const float* __restrict__ sh_bm,
                                     float* __restrict__ sh_mnl, int ksub, int tc0){
  constexpr int NP = NPAIR[L];
  constexpr int DK = 2*L+1;
  float acc[DK][2];
  #pragma unroll
  for (int k=0;k<DK;k++){ acc[k][0]=0.f; acc[k][1]=0.f; }
  const float* wb = wt + (size_t)tc0*256 + ksub*4;
  #pragma unroll
  for (int p=0;p<NP;p++){
    const float4 w0 = *(const float4*)(wb + (size_t)p*4096);
    const float4 w1 = *(const float4*)(wb + (size_t)p*4096 + 256);
    #pragma unroll
    for (int k=0;k<DK;k++){
      const float4 bk = *(const float4*)&sh_bm[(ROWB[L] + p*DK + k)*256 + ksub*4];
      acc[k][0] += bk.x*w0.x + bk.y*w0.y + bk.z*w0.z + bk.w*w0.w;
      acc[k][1] += bk.x*w1.x + bk.y*w1.y + bk.z*w1.z + bk.w*w1.w;
    }
  }
  #pragma unroll
  for (int k=0;k<DK;k++){
    #pragma unroll
    for (int off=32; off; off>>=1){
      acc[k][0] += __shfl_xor(acc[k][0], off);
      acc[k][1] += __shfl_xor(acc[k][1], off);
    }
  }
  if (ksub == 0) {
    #pragma unroll
    for (int k=0;k<DK;k++){
      sh_mnl[VOFF[L] + k*16 + tc0    ] = acc[k][0];
      sh_mnl[VOFF[L] + k*16 + tc0 + 1] = acc[k][1];
    }
  }
}

// ---------------- K2: CG products + mixing + last-block normalize ----------------
__global__ __launch_bounds__(512, 2)
void k_main(const float* __restrict__ wrel0, const float* __restrict__ wrel1, const float* __restrict__ wrel2,
            const float* __restrict__ ws_c, float* __restrict__ ws, float* __restrict__ out)
{
  __shared__ __align__(16) float sh_bm[51*256];  // ALL CG rows: l0 0-2, l1 3-20, l2 21-50
  __shared__ float sh_wrel[3840];
  __shared__ float sh_mnl[144];
  __shared__ float sh_S[9];
  __shared__ float sh_rel[6*144];
  __shared__ float sh_acc[144];
  __shared__ float sh_r[96];
  __shared__ float sh_d[3];
  __shared__ int   sh_last;

  const int t  = threadIdx.x;
  const int bi = blockIdx.x;
  float* part = ws + PART_OFF;

  // stage wrel into LDS (coalesced)
  for (int i=t; i<3840; i+=512){
    float v;
    if (i < 768)       v = wrel0[i];
    else if (i < 2304) v = wrel1[i-768];
    else               v = wrel2[i-2304];
    sh_wrel[i] = v;
  }
  // per-thread vmp fragments
  const int bc = (t>>4)&15, bd = t&15;
  float v_c[9], v_d[9];
  {
    const float* vb = ws_c + VMP_OFF + (size_t)bi*144;
    #pragma unroll
    for (int r=0;r<9;r++){ v_c[r] = vb[FOFF[r]+bc]; v_d[r] = vb[FOFF[r]+bd]; }
  }
  if (t < 9) sh_S[t] = ws_c[S_OFF + (size_t)bi*16 + t];

  const int tg = t>>6, ksub = t&63;
  const int tc0 = tg*2;

  // -------- Phase B: one build of all 51 rows, one barrier-free mix region --------
  {
    const int tt = t & 255;
    if (t < 256){
      build_p<0,0>(sh_bm,v_c,v_d,tt); build_p<0,1>(sh_bm,v_c,v_d,tt); build_p<0,2>(sh_bm,v_c,v_d,tt);
      build_p<1,0>(sh_bm,v_c,v_d,tt); build_p<1,1>(sh_bm,v_c,v_d,tt); build_p<1,2>(sh_bm,v_c,v_d,tt);
      build_p<2,0>(sh_bm,v_c,v_d,tt); build_p<2,1>(sh_bm,v_c,v_d,tt); build_p<2,2>(sh_bm,v_c,v_d,tt);
    } else {
      build_p<1,3>(sh_bm,v_c,v_d,tt); build_p<1,4>(sh_bm,v_c,v_d,tt); build_p<1,5>(sh_bm,v_c,v_d,tt);
      build_p<2,3>(sh_bm,v_c,v_d,tt); build_p<2,4>(sh_bm,v_c,v_d,tt); build_p<2,5>(sh_bm,v_c,v_d,tt);
    }
  }
  __syncthreads();
  mixl<0>(ws_c + WT_OFF + WTL[0], sh_bm, sh_mnl, ksub, tc0);
  mixl<1>(ws_c + WT_OFF + WTL[1], sh_bm, sh_mnl, ksub, tc0);
  mixl<2>(ws_c + WT_OFF + WTL[2], sh_bm, sh_mnl, ksub, tc0);
  __syncthreads();

  // -------- Phase C: rel-level CG (j-summed sph) + wrel mixing --------
  int l=0, f=0;
  if (t < 16)       { l=0; f=t;    }
  else if (t < 64)  { l=1; f=t-16; }
  else if (t < 144) { l=2; f=t-64; }
  const int k = f>>4, tc = f&15;

  if (t < 144) {
    const int np = NPAIR[l];
    #pragma unroll
    for (int p=0; p<6; p++) {
      if (p < np) {
        const int l1 = PAIRS[l][p][0], l2 = PAIRS[l][p][1];
        const int d2 = 2*l2+1;
        const int coff = OFF3[l1*9+l2*3+l];
        const int dk = 2*l+1;
        const int m = k - l;
        float a = 0.f;
        const int lo = (-l1 > m-l2) ? -l1 : m-l2;
        const int hi = ( l1 < m+l2) ?  l1 : m+l2;
        #pragma unroll
        for (int m1=-2; m1<=2; m1++) {
          if (m1 >= lo && m1 <= hi) {
            const int m2 = m - m1;
            const float C = CG.v[coff + ((m1+l1)*d2 + (m2+l2))*dk + k];
            a += C * sh_mnl[VOFF[l1] + (m1+l1)*TAU + tc] * sh_S[SOFF[l2] + (m2+l2)];
          }
        }
        sh_rel[p*144 + t] = a;
      }
    }
  }
  __syncthreads();
  if (t < 144) {
    const int np = NPAIR[l];
    float acc = 0.f;
    #pragma unroll
    for (int p=0; p<6; p++) {
      if (p < np) {
        const float* rrow = &sh_rel[p*144 + VOFF[l] + k*16];
        const float* wrow = &sh_wrel[WROFF[l] + p*256 + tc];
        #pragma unroll
        for (int c=0; c<16; c++)
          acc += rrow[c] * wrow[c*16];
      }
    }
    out[OUT_OFF[l] + ((size_t)bi*(2*l+1) + k)*TAU + tc] = acc;
    sh_acc[t] = acc;
  }
  __syncthreads();
  if (t < 48) {
    const int ll = t>>4, q = t&15;
    const int n = 2*ll+1;
    float a = 0.f;
    for (int i=0;i<n;i++) a += sh_acc[VOFF[ll] + i*16 + q];
    sh_r[t] = a;
  }
  __syncthreads();
  if (t < 3) {
    float a = 0.f;
    #pragma unroll
    for (int q=0;q<16;q++) a += sh_r[t*16+q];
    part[t*512 + bi] = a;   // plain store — zero contention
  }

  // -------- Finish: last block reduces partials + normalizes (round-5 pattern) --------
  __threadfence();                     // release: out + part visible device-wide
  if (t == 0) sh_last = (atomicAdd((int*)(ws + CNT_OFF), 1) == 511);
  __syncthreads();
  if (!sh_last) return;
  __threadfence();                     // acquire

  if (t < 96){
    const int ll = t>>5, q = t&31;
    const float* p = part + ll*512 + q*16;
    float a=0.f;
    #pragma unroll
    for (int i=0;i<16;i++) a += p[i];
    sh_r[t] = a;
  }
  __syncthreads();
  if (t < 3){
    float a=0.f;
    const float* r = &sh_r[t*32];
    #pragma unroll
    for (int i=0;i<32;i++) a += r[i];
    sh_d[t] = a;
  }
  __syncthreads();
  const float d0 = sh_d[0], d1 = sh_d[1], d2 = sh_d[2];
  float4* o4 = (float4*)out;
  for (int i4=t; i4<18432; i4+=512){
    float4 v = o4[i4];
    const float dd = (i4 < 2048) ? d0 : ((i4 < 8192) ? d1 : d2);
    v.x/=dd; v.y/=dd; v.z/=dd; v.w/=dd;
    o4[i4] = v;
  }
}

extern "C" void kernel_launch(void* const* d_in, const int* in_sizes, int n_in,
                              void* d_out, int out_size, void* d_ws, size_t ws_size,
                              hipStream_t stream) {
  // setup_inputs order: v0,s0,wnl0,wrel0, v1,s1,wnl1,wrel1, v2,s2,wnl2,wrel2, conn
  const float* v0    = (const float*)d_in[0];
  const float* s0    = (const float*)d_in[1];
  const float* wnl0  = (const float*)d_in[2];
  const float* wrel0 = (const float*)d_in[3];
  const float* v1    = (const float*)d_in[4];
  const float* s1    = (const float*)d_in[5];
  const float* wnl1  = (const float*)d_in[6];
  const float* wrel1 = (const float*)d_in[7];
  const float* v2    = (const float*)d_in[8];
  const float* s2    = (const float*)d_in[9];
  const float* wnl2  = (const float*)d_in[10];
  const float* wrel2 = (const float*)d_in[11];
  const int*   conn  = (const int*)d_in[12];
  float* out = (float*)d_out;
  float* ws  = (float*)d_ws;

  k_prep<<<512, 512, 0, stream>>>(v0, v1, v2, s0, s1, s2,
                                  wnl0, wnl1, wnl2, conn, ws);
  k_main<<<512, 512, 0, stream>>>(wrel0, wrel1, wrel2, ws, ws, out);
}

// Round 12
// 107.738 us; speedup vs baseline: 1.6668x; 1.6668x over previous
//
#include <hip/hip_runtime.h>

// CGLayer: MAX_L=2, B=2, N=256, TAU=16 — 3-kernel pipeline (round-9 dataflow,
// vmp/S fused into the main kernel; NO device-scope fences — twice measured at
// ~80us aggregate; kernel boundaries provide cross-block visibility).
// Identity: sum_j of edge-level CG(rep, sph) commutes with the j-sum because rep is
// broadcast along j => per-node work after S[bi][m2] = sum_j s[bi][j][m2].
// K1: wnl transpose (15 blocks, the only cross-block product).
// K2: vmp+S in-LDS + CG build (compile-time CG) + barrier-free mix + partial sums.
// K3: reduce 1536 partials + normalize (float4).

#define TAU 16

// ws layout (floats)
#define PART_OFF 768      // 3*512 per-block partial sums [l][bi]
#define WT_OFF   4096     // 15*4096 transposed wnl tiles [tile][tc][cd]

// ---------------- compile-time CG table ----------------
constexpr double cfact(int n){ double r=1.0; for(int i=2;i<=n;i++) r*=i; return r; }
constexpr double csqrt(double x){
  if (x<=0.0) return 0.0;
  double g = x<1.0 ? 1.0 : x;
  for (int i=0;i<80;i++) g = 0.5*(g + x/g);
  return g;
}
constexpr double cg_c(int j1,int j2,int j3,int m1,int m2,int m3){
  if (m1+m2 != m3) return 0.0;
  double pre = csqrt((2.0*j3+1.0)*cfact(j3+j1-j2)*cfact(j3-j1+j2)*cfact(j1+j2-j3)/cfact(j1+j2+j3+1));
  pre *= csqrt(cfact(j3+m3)*cfact(j3-m3)*cfact(j1-m1)*cfact(j1+m1)*cfact(j2-m2)*cfact(j2+m2));
  int kmin = 0;
  if (j2-j3-m1 > kmin) kmin = j2-j3-m1;
  if (j1-j3+m2 > kmin) kmin = j1-j3+m2;
  int kmax = j1+j2-j3;
  if (j1-m1 < kmax) kmax = j1-m1;
  if (j2+m2 < kmax) kmax = j2+m2;
  double s = 0.0;
  for (int k=kmin;k<=kmax;k++){
    double d = cfact(k)*cfact(j1+j2-j3-k)*cfact(j1-m1-k)*cfact(j2+m2-k)*cfact(j3-j2+m1+k)*cfact(j3-j1-m2+k);
    s += (k & 1) ? (-1.0/d) : (1.0/d);
  }
  return pre*s;
}
struct CGTab { float v[615]; };
constexpr CGTab gen_cg(){
  CGTab t{};
  const int TRI[15][3] = {
    {0,0,0},{0,1,1},{0,2,2},{1,0,1},{1,1,0},{1,1,1},{1,1,2},{1,2,1},{1,2,2},
    {2,0,2},{2,1,1},{2,1,2},{2,2,0},{2,2,1},{2,2,2}};
  int off = 0;
  for (int tr=0;tr<15;tr++){
    const int l1=TRI[tr][0], l2=TRI[tr][1], l=TRI[tr][2];
    for (int i1=0;i1<2*l1+1;i1++)
      for (int i2=0;i2<2*l2+1;i2++)
        for (int ik=0;ik<2*l+1;ik++)
          t.v[off++] = (float)cg_c(l1,l2,l,i1-l1,i2-l2,ik-l);
  }
  return t;
}
constexpr CGTab CG = gen_cg();

constexpr int OFF3[27] = {
  0,-1,-1,  -1,1,-1,   -1,-1,10,
  -1,35,-1, 44,53,80,  -1,125,170,
  -1,-1,245,-1,270,315,390,415,490};
constexpr int PAIRS[3][6][2] = {
  {{0,0},{1,1},{2,2},{0,0},{0,0},{0,0}},
  {{0,1},{1,0},{1,1},{1,2},{2,1},{2,2}},
  {{0,2},{1,1},{1,2},{2,0},{2,1},{2,2}}};
constexpr int VOFF[3]   = {0,16,64};
constexpr int SOFF[3]   = {0,1,4};
constexpr int OUT_OFF[3]= {0,8192,32768};
constexpr int NPAIR[3]  = {3,6,6};
constexpr int FOFF[9]   = {0,16,32,48,64,80,96,112,128};
constexpr int WROFF[3]  = {0,768,2304};
constexpr int WTL[3]    = {0,12288,36864};
constexpr int ROWB[3]   = {0,3,21};

__device__ constexpr int RIDX(int l, int mi){ return l==0 ? 0 : (l==1 ? 1+mi : 4+mi); }

// ---------------- K1: wnl transpose (only cross-block product) ----------------
__global__ __launch_bounds__(256)
void k_wt(const float* __restrict__ wnl0, const float* __restrict__ wnl1, const float* __restrict__ wnl2,
          float* __restrict__ ws)
{
  const int tile = blockIdx.x;   // 0..14
  const int cd = threadIdx.x;
  const float* src = (tile<3) ? (wnl0 + (size_t)tile*4096)
                   : (tile<9) ? (wnl1 + (size_t)(tile-3)*4096)
                              : (wnl2 + (size_t)(tile-9)*4096);
  float* dst = ws + WT_OFF + (size_t)tile*4096;
  const float4 r0 = *(const float4*)(src + cd*16);
  const float4 r1 = *(const float4*)(src + cd*16 + 4);
  const float4 r2 = *(const float4*)(src + cd*16 + 8);
  const float4 r3 = *(const float4*)(src + cd*16 + 12);
  dst[ 0*256+cd]=r0.x; dst[ 1*256+cd]=r0.y; dst[ 2*256+cd]=r0.z; dst[ 3*256+cd]=r0.w;
  dst[ 4*256+cd]=r1.x; dst[ 5*256+cd]=r1.y; dst[ 6*256+cd]=r1.z; dst[ 7*256+cd]=r1.w;
  dst[ 8*256+cd]=r2.x; dst[ 9*256+cd]=r2.y; dst[10*256+cd]=r2.z; dst[11*256+cd]=r2.w;
  dst[12*256+cd]=r3.x; dst[13*256+cd]=r3.y; dst[14*256+cd]=r3.z; dst[15*256+cd]=r3.w;
}

// ---------------- K2 helpers ----------------
template<int L, int P>
__device__ __forceinline__ void build_p(float* __restrict__ dst,
                                        const float (&v_c)[9], const float (&v_d)[9], int tt){
  constexpr int l1 = PAIRS[L][P][0], l2 = PAIRS[L][P][1];
  constexpr int d2 = 2*l2+1, dkk = 2*L+1;
  constexpr int coff = OFF3[l1*9+l2*3+L];
  constexpr int row0 = ROWB[L] + P*dkk;
  #pragma unroll
  for (int kk=0; kk<dkk; kk++){
    const int m = kk - L;
    float a = 0.f;
    #pragma unroll
    for (int m1=-l1; m1<=l1; m1++){
      const int m2 = m - m1;
      if (m2 >= -l2 && m2 <= l2){
        const float C = CG.v[coff + ((m1+l1)*d2 + (m2+l2))*dkk + kk];
        a += C * v_c[RIDX(l1,m1+l1)] * v_d[RIDX(l2,m2+l2)];
      }
    }
    dst[(row0 + kk)*256 + tt] = a;
  }
}

template<int L>
__device__ __forceinline__ void mixl(const float* __restrict__ wt, const float* __restrict__ sh_bm,
                                     float* __restrict__ sh_mnl, int ksub, int tc0){
  constexpr int NP = NPAIR[L];
  constexpr int DK = 2*L+1;
  float acc[DK][2];
  #pragma unroll
  for (int k=0;k<DK;k++){ acc[k][0]=0.f; acc[k][1]=0.f; }
  const float* wb = wt + (size_t)tc0*256 + ksub*4;
  #pragma unroll
  for (int p=0;p<NP;p++){
    const float4 w0 = *(const float4*)(wb + (size_t)p*4096);
    const float4 w1 = *(const float4*)(wb + (size_t)p*4096 + 256);
    #pragma unroll
    for (int k=0;k<DK;k++){
      const float4 bk = *(const float4*)&sh_bm[(ROWB[L] + p*DK + k)*256 + ksub*4];
      acc[k][0] += bk.x*w0.x + bk.y*w0.y + bk.z*w0.z + bk.w*w0.w;
      acc[k][1] += bk.x*w1.x + bk.y*w1.y + bk.z*w1.z + bk.w*w1.w;
    }
  }
  #pragma unroll
  for (int k=0;k<DK;k++){
    #pragma unroll
    for (int off=32; off; off>>=1){
      acc[k][0] += __shfl_xor(acc[k][0], off);
      acc[k][1] += __shfl_xor(acc[k][1], off);
    }
  }
  if (ksub == 0) {
    #pragma unroll
    for (int k=0;k<DK;k++){
      sh_mnl[VOFF[L] + k*16 + tc0    ] = acc[k][0];
      sh_mnl[VOFF[L] + k*16 + tc0 + 1] = acc[k][1];
    }
  }
}

// ---------------- K2: vmp+S in-LDS + CG products + mixing + partials ----------------
__global__ __launch_bounds__(512, 2)
void k_main(const float* __restrict__ v0, const float* __restrict__ v1, const float* __restrict__ v2,
            const float* __restrict__ s0, const float* __restrict__ s1, const float* __restrict__ s2,
            const float* __restrict__ wrel0, const float* __restrict__ wrel1, const float* __restrict__ wrel2,
            const int* __restrict__ conn, const float* __restrict__ ws_c,
            float* __restrict__ out, float* __restrict__ part)
{
  __shared__ __align__(16) float sh_bm[51*256];  // CG rows: l0 0-2, l1 3-20, l2 21-50
  __shared__ float sh_wrel[3840];
  __shared__ float sh_conn[256];
  __shared__ float sh_v[3][144];
  __shared__ float sh_vmp[144];
  __shared__ float sh_mnl[144];
  __shared__ float sh_S[9];
  __shared__ float sh_rel[6*144];
  __shared__ float sh_acc[144];
  __shared__ float sh_r[48];

  const int t  = threadIdx.x;
  const int bi = blockIdx.x;
  const int b  = bi >> 8;

  // ---- Phase A: conn + wrel stage, then vmp (3-way j-split) + S ----
  if (t < 256) sh_conn[t] = (float)conn[((size_t)bi<<8) + t];
  for (int i=t; i<3840; i+=512){
    float v;
    if (i < 768)       v = wrel0[i];
    else if (i < 2304) v = wrel1[i-768];
    else               v = wrel2[i-2304];
    sh_wrel[i] = v;
  }
  __syncthreads();

  if (t < 432) {
    // vmp third h: j in [j0, j0+cnt)
    const int h  = (t >= 288) ? 2 : ((t >= 144) ? 1 : 0);
    const int tt = t - h*144;
    const int j0 = h*86;
    const int cnt = (h==2) ? 84 : 86;
    int l, m, c;
    if (tt < 16)      { l=0; m=0;          c=tt;    }
    else if (tt < 64) { l=1; m=(tt-16)>>4; c=tt&15; }
    else              { l=2; m=(tt-64)>>4; c=tt&15; }
    const float* vl = (l==0) ? v0 : (l==1) ? v1 : v2;
    const int dm = 2*l+1;
    const int stride = dm*TAU;
    const float* base = vl + (((size_t)b*256 + j0)*dm + m)*TAU + c;
    const float* cr = &sh_conn[j0];
    float a[8];
    #pragma unroll
    for (int q=0;q<8;q++) a[q]=0.f;
    int j=0;
    for (; j+8<=cnt; j+=8){
      #pragma unroll
      for (int q=0;q<8;q++) a[q] += cr[j+q]*base[(j+q)*stride];
    }
    for (int q=0; j+q<cnt; q++) a[q] += cr[j+q]*base[(j+q)*stride];
    sh_v[h][tt] = ((a[0]+a[1])+(a[2]+a[3])) + ((a[4]+a[5])+(a[6]+a[7]));
  } else if (t >= 448) {
    // S[m] = sum_j s_l[bi][j][m] — one wave, shfl reduce, straight to LDS
    const int lane = t - 448;
    const float* p0 = s0 + (size_t)bi*256;
    const float* p1 = s1 + (size_t)bi*768;
    const float* p2 = s2 + (size_t)bi*1280;
    float a[9];
    #pragma unroll
    for (int m=0;m<9;m++) a[m]=0.f;
    #pragma unroll
    for (int q=0;q<4;q++){
      const int j = lane + q*64;
      a[0] += p0[j];
      a[1] += p1[3*j+0]; a[2] += p1[3*j+1]; a[3] += p1[3*j+2];
      #pragma unroll
      for (int k=0;k<5;k++) a[4+k] += p2[5*j+k];
    }
    #pragma unroll
    for (int m=0;m<9;m++){
      #pragma unroll
      for (int off=32; off; off>>=1) a[m] += __shfl_xor(a[m], off);
    }
    if (lane == 0) {
      #pragma unroll
      for (int m=0;m<9;m++) sh_S[m] = a[m];
    }
  }
  __syncthreads();
  if (t < 144) sh_vmp[t] = (sh_v[0][t] + sh_v[1][t]) + sh_v[2][t];
  __syncthreads();

  // per-thread vmp fragments
  const int bc = (t>>4)&15, bd = t&15;
  float v_c[9], v_d[9];
  #pragma unroll
  for (int r=0;r<9;r++){ v_c[r] = sh_vmp[FOFF[r]+bc]; v_d[r] = sh_vmp[FOFF[r]+bd]; }

  const int tg = t>>6, ksub = t&63;
  const int tc0 = tg*2;

  // ---- Phase B: one build of all 51 rows, one barrier-free mix region ----
  {
    const int tt = t & 255;
    if (t < 256){
      build_p<0,0>(sh_bm,v_c,v_d,tt); build_p<0,1>(sh_bm,v_c,v_d,tt); build_p<0,2>(sh_bm,v_c,v_d,tt);
      build_p<1,0>(sh_bm,v_c,v_d,tt); build_p<1,1>(sh_bm,v_c,v_d,tt); build_p<1,2>(sh_bm,v_c,v_d,tt);
      build_p<2,0>(sh_bm,v_c,v_d,tt); build_p<2,1>(sh_bm,v_c,v_d,tt); build_p<2,2>(sh_bm,v_c,v_d,tt);
    } else {
      build_p<1,3>(sh_bm,v_c,v_d,tt); build_p<1,4>(sh_bm,v_c,v_d,tt); build_p<1,5>(sh_bm,v_c,v_d,tt);
      build_p<2,3>(sh_bm,v_c,v_d,tt); build_p<2,4>(sh_bm,v_c,v_d,tt); build_p<2,5>(sh_bm,v_c,v_d,tt);
    }
  }
  __syncthreads();
  mixl<0>(ws_c + WT_OFF + WTL[0], sh_bm, sh_mnl, ksub, tc0);
  mixl<1>(ws_c + WT_OFF + WTL[1], sh_bm, sh_mnl, ksub, tc0);
  mixl<2>(ws_c + WT_OFF + WTL[2], sh_bm, sh_mnl, ksub, tc0);
  __syncthreads();

  // ---- Phase C: rel-level CG (j-summed sph) + wrel mixing ----
  int l=0, f=0;
  if (t < 16)       { l=0; f=t;    }
  else if (t < 64)  { l=1; f=t-16; }
  else if (t < 144) { l=2; f=t-64; }
  const int k = f>>4, tc = f&15;

  if (t < 144) {
    const int np = NPAIR[l];
    #pragma unroll
    for (int p=0; p<6; p++) {
      if (p < np) {
        const int l1 = PAIRS[l][p][0], l2 = PAIRS[l][p][1];
        const int d2 = 2*l2+1;
        const int coff = OFF3[l1*9+l2*3+l];
        const int dk = 2*l+1;
        const int m = k - l;
        float a = 0.f;
        const int lo = (-l1 > m-l2) ? -l1 : m-l2;
        const int hi = ( l1 < m+l2) ?  l1 : m+l2;
        #pragma unroll
        for (int m1=-2; m1<=2; m1++) {
          if (m1 >= lo && m1 <= hi) {
            const int m2 = m - m1;
            const float C = CG.v[coff + ((m1+l1)*d2 + (m2+l2))*dk + k];
            a += C * sh_mnl[VOFF[l1] + (m1+l1)*TAU + tc] * sh_S[SOFF[l2] + (m2+l2)];
          }
        }
        sh_rel[p*144 + t] = a;
      }
    }
  }
  __syncthreads();
  if (t < 144) {
    const int np = NPAIR[l];
    float acc = 0.f;
    #pragma unroll
    for (int p=0; p<6; p++) {
      if (p < np) {
        const float* rrow = &sh_rel[p*144 + VOFF[l] + k*16];
        const float* wrow = &sh_wrel[WROFF[l] + p*256 + tc];
        #pragma unroll
        for (int c=0; c<16; c++)
          acc += rrow[c] * wrow[c*16];
      }
    }
    out[OUT_OFF[l] + ((size_t)bi*(2*l+1) + k)*TAU + tc] = acc;
    sh_acc[t] = acc;
  }
  __syncthreads();
  if (t < 48) {
    const int ll = t>>4, q = t&15;
    const int n = 2*ll+1;
    float a = 0.f;
    for (int i=0;i<n;i++) a += sh_acc[VOFF[ll] + i*16 + q];
    sh_r[t] = a;
  }
  __syncthreads();
  if (t < 3) {
    float a = 0.f;
    #pragma unroll
    for (int q=0;q<16;q++) a += sh_r[t*16+q];
    part[t*512 + bi] = a;   // plain store — kernel boundary provides visibility
  }
}

// ---------------- K3: reduce partials + normalize (float4) ----------------
__global__ __launch_bounds__(256)
void k_norm(float* __restrict__ out, const float* __restrict__ part){
  __shared__ float sh_r[96];
  __shared__ float sh_d[3];
  const int t = threadIdx.x;
  if (t < 96){
    const int l = t>>5, q = t&31;
    const float* p = part + l*512 + q*16;
    float a=0.f;
    #pragma unroll
    for (int i=0;i<16;i++) a += p[i];
    sh_r[t] = a;
  }
  __syncthreads();
  if (t < 3){
    float a=0.f;
    const float* r = &sh_r[t*32];
    #pragma unroll
    for (int i=0;i<32;i++) a += r[i];
    sh_d[t] = a;
  }
  __syncthreads();
  const int i4 = blockIdx.x*256 + t;   // 72*256 = 18432 float4 = 73728 floats
  if (i4 < 18432){
    const float dd = (i4 < 2048) ? sh_d[0] : ((i4 < 8192) ? sh_d[1] : sh_d[2]);
    float4 v = ((const float4*)out)[i4];
    v.x/=dd; v.y/=dd; v.z/=dd; v.w/=dd;
    ((float4*)out)[i4] = v;
  }
}

extern "C" void kernel_launch(void* const* d_in, const int* in_sizes, int n_in,
                              void* d_out, int out_size, void* d_ws, size_t ws_size,
                              hipStream_t stream) {
  // setup_inputs order: v0,s0,wnl0,wrel0, v1,s1,wnl1,wrel1, v2,s2,wnl2,wrel2, conn
  const float* v0    = (const float*)d_in[0];
  const float* s0    = (const float*)d_in[1];
  const float* wnl0  = (const float*)d_in[2];
  const float* wrel0 = (const float*)d_in[3];
  const float* v1    = (const float*)d_in[4];
  const float* s1    = (const float*)d_in[5];
  const float* wnl1  = (const float*)d_in[6];
  const float* wrel1 = (const float*)d_in[7];
  const float* v2    = (const float*)d_in[8];
  const float* s2    = (const float*)d_in[9];
  const float* wnl2  = (const float*)d_in[10];
  const float* wrel2 = (const float*)d_in[11];
  const int*   conn  = (const int*)d_in[12];
  float* out = (float*)d_out;
  float* ws  = (float*)d_ws;
  float* part = ws + PART_OFF;

  k_wt  <<<15,  256, 0, stream>>>(wnl0, wnl1, wnl2, ws);
  k_main<<<512, 512, 0, stream>>>(v0, v1, v2, s0, s1, s2,
                                  wrel0, wrel1, wrel2, conn, ws, out, part);
  k_norm<<<72,  256, 0, stream>>>(out, part);
}